// Round 1
// baseline (1108.509 us; speedup 1.0000x reference)
//
#include <hip/hip_runtime.h>

#define N_NODES 25000
#define E_EDGES 400000
#define KM 200   // message channels

// ---------------- sort-by-dst (CSR build) ----------------

__global__ void zero_i32(int* __restrict__ p, int n) {
  int i = blockIdx.x * blockDim.x + threadIdx.x;
  if (i < n) p[i] = 0;
}

__global__ void hist_kernel(const int* __restrict__ edges, int* __restrict__ hist) {
  int e = blockIdx.x * blockDim.x + threadIdx.x;
  if (e < E_EDGES) atomicAdd(&hist[edges[E_EDGES + e]], 1);
}

__global__ void scan_kernel(const int* __restrict__ hist, int* __restrict__ off,
                            int* __restrict__ cursor) {
  __shared__ int sums[1024];
  const int CH = (N_NODES + 1023) / 1024;  // 25
  int tid = threadIdx.x;
  int base = tid * CH;
  int s = 0;
  for (int i = 0; i < CH; i++) {
    int idx = base + i;
    if (idx < N_NODES) s += hist[idx];
  }
  sums[tid] = s;
  __syncthreads();
  for (int d = 1; d < 1024; d <<= 1) {
    int v = (tid >= d) ? sums[tid - d] : 0;
    __syncthreads();
    sums[tid] += v;
    __syncthreads();
  }
  int run = (tid == 0) ? 0 : sums[tid - 1];
  for (int i = 0; i < CH; i++) {
    int idx = base + i;
    if (idx < N_NODES) {
      off[idx] = run;
      cursor[idx] = run;
      run += hist[idx];
    }
  }
  if (tid == 1023) off[N_NODES] = run;  // == E
}

__global__ void scatter_kernel(const int* __restrict__ edges, int* __restrict__ cursor,
                               int* __restrict__ srcS, int* __restrict__ dstS) {
  int e = blockIdx.x * blockDim.x + threadIdx.x;
  if (e < E_EDGES) {
    int s = edges[e];
    int d = edges[E_EDGES + e];
    int pos = atomicAdd(&cursor[d], 1);
    srcS[pos] = s;
    dstS[pos] = d;
  }
}

// ---------------- per-layer kernels ----------------

// Node prep: xr = relu?(xin); A = xr @ Wm1[0:CIN] + bm1; B = xr @ Wm1[CIN:2CIN]
template <int CIN>
__global__ void prep_kernel(const float* __restrict__ xin, int do_relu,
                            const float* __restrict__ Wm1, const float* __restrict__ bm1,
                            float* __restrict__ A, float* __restrict__ B,
                            float* __restrict__ xr) {
  const int NT = 8;
  int k = threadIdx.x;  // 0..255, active k<KM
  float wa[CIN], wb[CIN];
  float bm = 0.f;
  if (k < KM) {
    bm = bm1[k];
#pragma unroll
    for (int c = 0; c < CIN; c++) {
      wa[c] = Wm1[c * KM + k];
      wb[c] = Wm1[(CIN + c) * KM + k];
    }
  }
  int n0 = blockIdx.x * NT;
  for (int i = 0; i < NT; i++) {
    int n = n0 + i;
    float xv[CIN];
#pragma unroll
    for (int c = 0; c < CIN; c++) {
      float v = xin[n * CIN + c];
      xv[c] = do_relu ? fmaxf(v, 0.f) : v;
    }
    if (k < CIN) xr[n * CIN + k] = xv[k];
    if (k < KM) {
      float a = bm, b = 0.f;
#pragma unroll
      for (int c = 0; c < CIN; c++) {
        a += xv[c] * wa[c];
        b += xv[c] * wb[c];
      }
      A[n * KM + k] = a;
      B[n * KM + k] = b;
    }
  }
}

// Edge kernel: one thread per (dst-sorted) edge.
// h_k = relu(A[dst][k] + B[src][k]); gate = h @ Wm2 + bm2; gd[c][e] = gate[c]*(x_i[c]-x_j[c])
template <int CIN>
__global__ void __launch_bounds__(256) edge_kernel(
    const int* __restrict__ srcS, const int* __restrict__ dstS,
    const float* __restrict__ A, const float* __restrict__ B,
    const float* __restrict__ Wm2, const float* __restrict__ bm2,
    const float* __restrict__ xr, float* __restrict__ gd) {
  int e = blockIdx.x * blockDim.x + threadIdx.x;
  if (e >= E_EDGES) return;
  int src = srcS[e];
  int dst = dstS[e];
  const float* Ar = A + (size_t)dst * KM;
  const float* Br = B + (size_t)src * KM;
  float gate[CIN];
#pragma unroll
  for (int c = 0; c < CIN; c++) gate[c] = bm2[c];
#pragma unroll 2
  for (int k = 0; k < KM; k += 4) {
    float4 a4 = *(const float4*)(Ar + k);
    float4 b4 = *(const float4*)(Br + k);
    float h0 = fmaxf(a4.x + b4.x, 0.f);
    float h1 = fmaxf(a4.y + b4.y, 0.f);
    float h2 = fmaxf(a4.z + b4.z, 0.f);
    float h3 = fmaxf(a4.w + b4.w, 0.f);
#pragma unroll
    for (int c = 0; c < CIN; c++) {
      gate[c] += h0 * Wm2[(k + 0) * CIN + c] + h1 * Wm2[(k + 1) * CIN + c] +
                 h2 * Wm2[(k + 2) * CIN + c] + h3 * Wm2[(k + 3) * CIN + c];
    }
  }
  const float* xi = xr + (size_t)dst * CIN;
  const float* xj = xr + (size_t)src * CIN;
#pragma unroll
  for (int c = 0; c < CIN; c++) {
    gd[(size_t)c * E_EDGES + e] = gate[c] * (xi[c] - xj[c]);
  }
}

// Aggregate: acc_pre[n][c] = sum over CSR segment of gd[c][e]; then
// out[n][o] = acc_pre@W2 + deg*b2 + xr@W1 + b1
template <int CIN, int COUT>
__global__ void agg_kernel(const float* __restrict__ gd, const int* __restrict__ off,
                           const float* __restrict__ xr,
                           const float* __restrict__ W1, const float* __restrict__ b1,
                           const float* __restrict__ W2, const float* __restrict__ b2,
                           float* __restrict__ out) {
  int n = blockIdx.x * blockDim.x + threadIdx.x;
  if (n >= N_NODES) return;
  int s = off[n];
  int t = off[n + 1];
  float aggp[CIN];
#pragma unroll
  for (int c = 0; c < CIN; c++) {
    float v = 0.f;
    for (int e = s; e < t; e++) v += gd[(size_t)c * E_EDGES + e];
    aggp[c] = v;
  }
  float xv[CIN];
#pragma unroll
  for (int c = 0; c < CIN; c++) xv[c] = xr[n * CIN + c];
  float deg = (float)(t - s);
#pragma unroll
  for (int o = 0; o < COUT; o++) {
    float v = b1[o] + deg * b2[o];
#pragma unroll
    for (int c = 0; c < CIN; c++) v += aggp[c] * W2[c * COUT + o] + xv[c] * W1[c * COUT + o];
    out[n * COUT + o] = v;
  }
}

// ---------------- launch ----------------

extern "C" void kernel_launch(void* const* d_in, const int* in_sizes, int n_in,
                              void* d_out, int out_size, void* d_ws, size_t ws_size,
                              hipStream_t stream) {
  const float* features = (const float*)d_in[0];
  const int* edges = (const int*)d_in[1];
  // d_in[2] = weights (unused by reference)

  // per-layer params: W1,b1,Wm1,bm1,Wm2,bm2,W2,b2 at bases 3 (d), 11 (h), 19 (o)
  const float *dW1 = (const float*)d_in[3], *db1 = (const float*)d_in[4],
              *dWm1 = (const float*)d_in[5], *dbm1 = (const float*)d_in[6],
              *dWm2 = (const float*)d_in[7], *dbm2 = (const float*)d_in[8],
              *dW2 = (const float*)d_in[9], *db2 = (const float*)d_in[10];
  const float *hW1 = (const float*)d_in[11], *hb1 = (const float*)d_in[12],
              *hWm1 = (const float*)d_in[13], *hbm1 = (const float*)d_in[14],
              *hWm2 = (const float*)d_in[15], *hbm2 = (const float*)d_in[16],
              *hW2 = (const float*)d_in[17], *hb2 = (const float*)d_in[18];
  const float *oW1 = (const float*)d_in[19], *ob1 = (const float*)d_in[20],
              *oWm1 = (const float*)d_in[21], *obm1 = (const float*)d_in[22],
              *oWm2 = (const float*)d_in[23], *obm2 = (const float*)d_in[24],
              *oW2 = (const float*)d_in[25], *ob2 = (const float*)d_in[26];

  // workspace layout (floats)
  float* fws = (float*)d_ws;
  size_t o = 0;
  float* A = fws + o;    o += (size_t)N_NODES * KM;   // 5.0M
  float* Bm = fws + o;   o += (size_t)N_NODES * KM;   // 5.0M
  float* gd = fws + o;   o += (size_t)20 * E_EDGES;   // 8.0M
  float* xr = fws + o;   o += (size_t)N_NODES * 20;
  float* acc1 = fws + o; o += (size_t)N_NODES * 20;
  float* acc2 = fws + o; o += (size_t)N_NODES * 20;
  float* xr0 = fws + o;  o += 25008;
  int* ip = (int*)(fws + o);
  int* hist = ip;   ip += N_NODES;
  int* off = ip;    ip += N_NODES + 4;
  int* cursor = ip; ip += N_NODES;
  int* srcS = ip;   ip += E_EDGES;
  int* dstS = ip;   ip += E_EDGES;

  const int B256 = 256;
  const int EDGE_G = (E_EDGES + B256 - 1) / B256;
  const int NODE_G = (N_NODES + B256 - 1) / B256;
  const int PREP_G = N_NODES / 8;  // 3125, exact

  // build dst-sorted edge list + CSR offsets (recomputed every launch)
  zero_i32<<<NODE_G, B256, 0, stream>>>(hist, N_NODES);
  hist_kernel<<<EDGE_G, B256, 0, stream>>>(edges, hist);
  scan_kernel<<<1, 1024, 0, stream>>>(hist, off, cursor);
  scatter_kernel<<<EDGE_G, B256, 0, stream>>>(edges, cursor, srcS, dstS);

  // layer d: 1 -> 20
  prep_kernel<1><<<PREP_G, B256, 0, stream>>>(features, 0, dWm1, dbm1, A, Bm, xr0);
  edge_kernel<1><<<EDGE_G, B256, 0, stream>>>(srcS, dstS, A, Bm, dWm2, dbm2, xr0, gd);
  agg_kernel<1, 20><<<NODE_G, B256, 0, stream>>>(gd, off, xr0, dW1, db1, dW2, db2, acc1);

  // 3 hidden layers: 20 -> 20 (relu applied to input inside prep)
  float* cur = acc1;
  float* nxt = acc2;
  for (int i = 0; i < 3; i++) {
    prep_kernel<20><<<PREP_G, B256, 0, stream>>>(cur, 1, hWm1, hbm1, A, Bm, xr);
    edge_kernel<20><<<EDGE_G, B256, 0, stream>>>(srcS, dstS, A, Bm, hWm2, hbm2, xr, gd);
    agg_kernel<20, 20><<<NODE_G, B256, 0, stream>>>(gd, off, xr, hW1, hb1, hW2, hb2, nxt);
    float* tmp = cur; cur = nxt; nxt = tmp;
  }

  // output layer: 20 -> 1 (no trailing relu)
  prep_kernel<20><<<PREP_G, B256, 0, stream>>>(cur, 1, oWm1, obm1, A, Bm, xr);
  edge_kernel<20><<<EDGE_G, B256, 0, stream>>>(srcS, dstS, A, Bm, oWm2, obm2, xr, gd);
  agg_kernel<20, 1><<<NODE_G, B256, 0, stream>>>(gd, off, xr, oW1, ob1, oW2, ob2,
                                                 (float*)d_out);
}

// Round 3
// 1046.501 us; speedup vs baseline: 1.0593x; 1.0593x over previous
//
#include <hip/hip_runtime.h>

#define N_NODES 25000
#define E_EDGES 400000
#define KM 200     // message channels
#define RS 224     // fused row stride (floats): 200 A/B + up to 20 x + pad

// ---------------- sort-by-dst (CSR build) ----------------

__global__ void zero_i32(int* __restrict__ p, int n) {
  int i = blockIdx.x * blockDim.x + threadIdx.x;
  if (i < n) p[i] = 0;
}

__global__ void hist_kernel(const int* __restrict__ edges, int* __restrict__ hist) {
  int e = blockIdx.x * blockDim.x + threadIdx.x;
  if (e < E_EDGES) atomicAdd(&hist[edges[E_EDGES + e]], 1);
}

__global__ void scan_kernel(const int* __restrict__ hist, int* __restrict__ off,
                            int* __restrict__ cursor) {
  __shared__ int sums[1024];
  const int CH = (N_NODES + 1023) / 1024;  // 25
  int tid = threadIdx.x;
  int base = tid * CH;
  int s = 0;
  for (int i = 0; i < CH; i++) {
    int idx = base + i;
    if (idx < N_NODES) s += hist[idx];
  }
  sums[tid] = s;
  __syncthreads();
  for (int d = 1; d < 1024; d <<= 1) {
    int v = (tid >= d) ? sums[tid - d] : 0;
    __syncthreads();
    sums[tid] += v;
    __syncthreads();
  }
  int run = (tid == 0) ? 0 : sums[tid - 1];
  for (int i = 0; i < CH; i++) {
    int idx = base + i;
    if (idx < N_NODES) {
      off[idx] = run;
      cursor[idx] = run;
      run += hist[idx];
    }
  }
  if (tid == 1023) off[N_NODES] = run;  // == E
}

__global__ void scatter_kernel(const int* __restrict__ edges, int* __restrict__ cursor,
                               int* __restrict__ srcS, int* __restrict__ dstS) {
  int e = blockIdx.x * blockDim.x + threadIdx.x;
  if (e < E_EDGES) {
    int s = edges[e];
    int d = edges[E_EDGES + e];
    int pos = atomicAdd(&cursor[d], 1);
    srcS[pos] = s;
    dstS[pos] = d;
  }
}

// ---------------- per-layer kernels ----------------

// Node prep: xv = relu?(xin)
//   A2[n] = [ xv@Wm1_top + bm1 (200) | xv (CIN) | pad ]   (stride RS floats)
//   B2[n] = [ xv@Wm1_bot       (200) | xv (CIN) | pad ]
//   xr[n][c] = xv  (compact copy for fin_kernel)
template <int CIN>
__global__ void prep_kernel(const float* __restrict__ xin, int do_relu,
                            const float* __restrict__ Wm1, const float* __restrict__ bm1,
                            float* __restrict__ A2, float* __restrict__ B2,
                            float* __restrict__ xr) {
  const int NT = 8;
  int k = threadIdx.x;  // 0..255
  float wa[CIN], wb[CIN];
  float bm = 0.f;
  if (k < KM) {
    bm = bm1[k];
#pragma unroll
    for (int c = 0; c < CIN; c++) {
      wa[c] = Wm1[c * KM + k];
      wb[c] = Wm1[(CIN + c) * KM + k];
    }
  }
  int n0 = blockIdx.x * NT;
  for (int i = 0; i < NT; i++) {
    int n = n0 + i;
    float xv[CIN];
#pragma unroll
    for (int c = 0; c < CIN; c++) {
      float v = xin[n * CIN + c];
      xv[c] = do_relu ? fmaxf(v, 0.f) : v;
    }
    size_t row = (size_t)n * RS;
    if (k < CIN) {
      xr[n * CIN + k] = xv[k];
      A2[row + KM + k] = xv[k];
      B2[row + KM + k] = xv[k];
    }
    if (k < KM) {
      float a = bm, b = 0.f;
#pragma unroll
      for (int c = 0; c < CIN; c++) {
        a += xv[c] * wa[c];
        b += xv[c] * wb[c];
      }
      A2[row + k] = a;
      B2[row + k] = b;
    }
  }
}

// Edge kernel: one thread per (dst-sorted) edge.
// h_k = relu(A2[dst][k] + B2[src][k]); gate = h@Wm2 + bm2;
// gd[c][e] = gate[c] * (xi[c] - xj[c])  (x tails live in the same rows)
template <int CIN>
__global__ void __launch_bounds__(256) edge_kernel(
    const int* __restrict__ srcS, const int* __restrict__ dstS,
    const float* __restrict__ A2, const float* __restrict__ B2,
    const float* __restrict__ Wm2, const float* __restrict__ bm2,
    float* __restrict__ gd) {
  // XCD-contiguous swizzle: round-robin hardware placement -> contiguous
  // dst-sorted edge range per XCD (A-rows ~2.8 MB/XCD fit the 4 MiB L2).
  int per = gridDim.x >> 3;  // gridDim.x is a multiple of 8
  int b2 = (blockIdx.x & 7) * per + (blockIdx.x >> 3);
  int e = b2 * 256 + threadIdx.x;
  if (e >= E_EDGES) return;
  int src = srcS[e];
  int dst = dstS[e];
  const float* Ar = A2 + (size_t)dst * RS;
  const float* Br = B2 + (size_t)src * RS;
  float gate[CIN];
#pragma unroll
  for (int c = 0; c < CIN; c++) gate[c] = bm2[c];
#pragma unroll 4
  for (int k = 0; k < KM; k += 4) {
    float4 a4 = *(const float4*)(Ar + k);
    float4 b4 = *(const float4*)(Br + k);
    float h0 = fmaxf(a4.x + b4.x, 0.f);
    float h1 = fmaxf(a4.y + b4.y, 0.f);
    float h2 = fmaxf(a4.z + b4.z, 0.f);
    float h3 = fmaxf(a4.w + b4.w, 0.f);
#pragma unroll
    for (int c = 0; c < CIN; c++) {
      gate[c] += h0 * Wm2[(k + 0) * CIN + c] + h1 * Wm2[(k + 1) * CIN + c] +
                 h2 * Wm2[(k + 2) * CIN + c] + h3 * Wm2[(k + 3) * CIN + c];
    }
  }
#pragma unroll
  for (int c = 0; c < CIN; c++) {
    gd[(size_t)c * E_EDGES + e] = gate[c] * (Ar[KM + c] - Br[KM + c]);
  }
}

// agg1: thread per (c, n): aggp[n][c] = sum over CSR segment of gd[c][e]
template <int CIN>
__global__ void agg1_kernel(const float* __restrict__ gd, const int* __restrict__ off,
                            float* __restrict__ aggp) {
  int idx = blockIdx.x * blockDim.x + threadIdx.x;
  if (idx >= CIN * N_NODES) return;
  int c = idx / N_NODES;
  int n = idx - c * N_NODES;
  int s = off[n];
  int t = off[n + 1];
  const float* g = gd + (size_t)c * E_EDGES;
  float v = 0.f;
  for (int e = s; e < t; e++) v += g[e];
  aggp[(size_t)n * CIN + c] = v;
}

// fin: thread per node: out[n][o] = aggp@W2 + deg*b2 + xr@W1 + b1
template <int CIN, int COUT>
__global__ void fin_kernel(const float* __restrict__ aggp, const int* __restrict__ off,
                           const float* __restrict__ xr,
                           const float* __restrict__ W1, const float* __restrict__ b1,
                           const float* __restrict__ W2, const float* __restrict__ b2,
                           float* __restrict__ out) {
  int n = blockIdx.x * blockDim.x + threadIdx.x;
  if (n >= N_NODES) return;
  float deg = (float)(off[n + 1] - off[n]);
  float ag[CIN], xv[CIN];
#pragma unroll
  for (int c = 0; c < CIN; c++) {
    ag[c] = aggp[(size_t)n * CIN + c];
    xv[c] = xr[(size_t)n * CIN + c];
  }
#pragma unroll
  for (int o = 0; o < COUT; o++) {
    float v = b1[o] + deg * b2[o];
#pragma unroll
    for (int c = 0; c < CIN; c++) v += ag[c] * W2[c * COUT + o] + xv[c] * W1[c * COUT + o];
    out[(size_t)n * COUT + o] = v;
  }
}

// ---------------- launch ----------------

extern "C" void kernel_launch(void* const* d_in, const int* in_sizes, int n_in,
                              void* d_out, int out_size, void* d_ws, size_t ws_size,
                              hipStream_t stream) {
  const float* features = (const float*)d_in[0];
  const int* edges = (const int*)d_in[1];
  // d_in[2] = weights (unused by reference)

  const float *dW1 = (const float*)d_in[3], *db1 = (const float*)d_in[4],
              *dWm1 = (const float*)d_in[5], *dbm1 = (const float*)d_in[6],
              *dWm2 = (const float*)d_in[7], *dbm2 = (const float*)d_in[8],
              *dW2 = (const float*)d_in[9], *db2 = (const float*)d_in[10];
  const float *hW1 = (const float*)d_in[11], *hb1 = (const float*)d_in[12],
              *hWm1 = (const float*)d_in[13], *hbm1 = (const float*)d_in[14],
              *hWm2 = (const float*)d_in[15], *hbm2 = (const float*)d_in[16],
              *hW2 = (const float*)d_in[17], *hb2 = (const float*)d_in[18];
  const float *oW1 = (const float*)d_in[19], *ob1 = (const float*)d_in[20],
              *oWm1 = (const float*)d_in[21], *obm1 = (const float*)d_in[22],
              *oWm2 = (const float*)d_in[23], *obm2 = (const float*)d_in[24],
              *oW2 = (const float*)d_in[25], *ob2 = (const float*)d_in[26];

  // workspace layout (float units)
  float* fws = (float*)d_ws;
  size_t o = 0;
  float* A2 = fws + o;   o += (size_t)N_NODES * RS;   // 5.6M
  float* B2 = fws + o;   o += (size_t)N_NODES * RS;   // 5.6M
  float* gd = fws + o;   o += (size_t)20 * E_EDGES;   // 8.0M
  float* xr = fws + o;   o += (size_t)N_NODES * 20;
  float* aggp = fws + o; o += (size_t)N_NODES * 20;
  float* acc1 = fws + o; o += (size_t)N_NODES * 20;
  float* acc2 = fws + o; o += (size_t)N_NODES * 20;
  int* ip = (int*)(fws + o);
  int* hist = ip;   ip += N_NODES;
  int* off = ip;    ip += N_NODES + 4;
  int* cursor = ip; ip += N_NODES;
  int* srcS = ip;   ip += E_EDGES;
  int* dstS = ip;   ip += E_EDGES;

  const int B256 = 256;
  const int EDGE_G = ((E_EDGES + B256 - 1) / B256 + 7) & ~7;  // 1568, multiple of 8
  const int NODE_G = (N_NODES + B256 - 1) / B256;
  const int PREP_G = N_NODES / 8;  // 3125, exact
  const int AGG1_G = (1 * N_NODES + B256 - 1) / B256;
  const int AGG20_G = (20 * N_NODES + B256 - 1) / B256;

  // build dst-sorted edge list + CSR offsets (recomputed every launch)
  zero_i32<<<NODE_G, B256, 0, stream>>>(hist, N_NODES);
  hist_kernel<<<(E_EDGES + B256 - 1) / B256, B256, 0, stream>>>(edges, hist);
  scan_kernel<<<1, 1024, 0, stream>>>(hist, off, cursor);
  scatter_kernel<<<(E_EDGES + B256 - 1) / B256, B256, 0, stream>>>(edges, cursor, srcS, dstS);

  // layer d: 1 -> 20
  prep_kernel<1><<<PREP_G, B256, 0, stream>>>(features, 0, dWm1, dbm1, A2, B2, xr);
  edge_kernel<1><<<EDGE_G, B256, 0, stream>>>(srcS, dstS, A2, B2, dWm2, dbm2, gd);
  agg1_kernel<1><<<AGG1_G, B256, 0, stream>>>(gd, off, aggp);
  fin_kernel<1, 20><<<NODE_G, B256, 0, stream>>>(aggp, off, xr, dW1, db1, dW2, db2, acc1);

  // 3 hidden layers: 20 -> 20 (relu applied to input inside prep)
  float* cur = acc1;
  float* nxt = acc2;
  for (int i = 0; i < 3; i++) {
    prep_kernel<20><<<PREP_G, B256, 0, stream>>>(cur, 1, hWm1, hbm1, A2, B2, xr);
    edge_kernel<20><<<EDGE_G, B256, 0, stream>>>(srcS, dstS, A2, B2, hWm2, hbm2, gd);
    agg1_kernel<20><<<AGG20_G, B256, 0, stream>>>(gd, off, aggp);
    fin_kernel<20, 20><<<NODE_G, B256, 0, stream>>>(aggp, off, xr, hW1, hb1, hW2, hb2, nxt);
    float* tmp = cur; cur = nxt; nxt = tmp;
  }

  // output layer: 20 -> 1 (no trailing relu)
  prep_kernel<20><<<PREP_G, B256, 0, stream>>>(cur, 1, oWm1, obm1, A2, B2, xr);
  edge_kernel<20><<<EDGE_G, B256, 0, stream>>>(srcS, dstS, A2, B2, oWm2, obm2, gd);
  agg1_kernel<20><<<AGG20_G, B256, 0, stream>>>(gd, off, aggp);
  fin_kernel<20, 1><<<NODE_G, B256, 0, stream>>>(aggp, off, xr, oW1, ob1, oW2, ob2,
                                                 (float*)d_out);
}